// Round 13
// baseline (1988.783 us; speedup 1.0000x reference)
//
#include <hip/hip_runtime.h>
#include <math.h>

// ---------------------------------------------------------------------------
// RNN_63153199120819 — Round 13: barrier-overlapped (software-pipelined) LSTM.
// R12 was neutral -> barrier ENCODING is not the lever. The ~10us phase is
// (barrier post+detect+skew) + (2 serialized load batches + 3 syncs + cells)
// all in series. This round moves the barrier-INDEPENDENT work — layer-0's
// u-half gates (u is pure input) — into the poll window: arrival inc, then
// layer-0 waves load u(t+2) and run 16 MFMAs into registers held across the
// barrier, then release-wait. Post-release path = h-loads + remaining MFMAs
// + cells only. Accumulation order unchanged -> bit-identical numerics.
// MLP: kTc 32->64, single scratch (ubuf in-place) — half the launches.
// ---------------------------------------------------------------------------

namespace {
constexpr int kT   = 128;
constexpr int kB   = 1024;
constexpr int kLag = 6;
constexpr int kH   = 256;
constexpr int kTc  = 64;          // MLP time chunk
constexpr int kMc  = kTc * kB;    // 65536 rows / chunk
constexpr int kGS  = 67;          // LDS gate row stride (f32)
constexpr int kLdsForce = 98304;  // >80KB => at most 1 block/CU
}

typedef _Float16 half8 __attribute__((ext_vector_type(8)));
typedef _Float16 half2 __attribute__((ext_vector_type(2)));
typedef float f32x4 __attribute__((ext_vector_type(4)));
typedef unsigned long long u64;

__device__ __forceinline__ float sigm(float x) {
    return 1.f / (1.f + exp2f(-1.4426950408889634f * x));
}
__device__ __forceinline__ float tanh_(float x) {
    return 2.f / (1.f + exp2f(-2.8853900817779268f * x)) - 1.f;
}

// ---- inline-asm memory ops ------------------------------------------------
__device__ __forceinline__ void ld_l2(half8& d, const _Float16* p) {
    asm volatile("global_load_dwordx4 %0, %1, off sc0"
                 : "=v"(d) : "v"(p) : "memory");
}
__device__ __forceinline__ void ld_pln(half8& d, const _Float16* p) {
    asm volatile("global_load_dwordx4 %0, %1, off"
                 : "=v"(d) : "v"(p) : "memory");
}
__device__ __forceinline__ void atomic_add_nr(unsigned int* p, unsigned int v) {
    asm volatile("global_atomic_add %0, %1, off"
                 :: "v"(p), "v"(v) : "memory");
}
__device__ __forceinline__ unsigned int atomic_rd(unsigned int* p) {
    unsigned int d;
    unsigned int z = 0u;
    asm volatile("global_atomic_add %0, %1, %2, off sc0\n\ts_waitcnt vmcnt(0)"
                 : "=v"(d) : "v"(p), "v"(z) : "memory");
    return d;
}
#define WAITCNT_HOLD8(A)                                                      \
    asm volatile("s_waitcnt vmcnt(0)"                                         \
        : "+v"(A[0]), "+v"(A[1]), "+v"(A[2]), "+v"(A[3]),                     \
          "+v"(A[4]), "+v"(A[5]), "+v"(A[6]), "+v"(A[7]))
#define WAITCNT_HOLD16(A)                                                     \
    asm volatile("s_waitcnt vmcnt(0)"                                         \
        : "+v"(A[0]), "+v"(A[1]), "+v"(A[2]), "+v"(A[3]),                     \
          "+v"(A[4]), "+v"(A[5]), "+v"(A[6]), "+v"(A[7]),                     \
          "+v"(A[8]), "+v"(A[9]), "+v"(A[10]), "+v"(A[11]),                   \
          "+v"(A[12]), "+v"(A[13]), "+v"(A[14]), "+v"(A[15]))

// ---------------- prep kernels ---------------------------------------------
__global__ __launch_bounds__(256)
void zero_fill(unsigned int* __restrict__ p)
{
    p[blockIdx.x * 256 + threadIdx.x] = 0u;
}

__global__ __launch_bounds__(256)
void cvt_f2h(const float* __restrict__ s, _Float16* __restrict__ d)
{
    const int i = blockIdx.x * 256 + threadIdx.x;
    d[i] = (_Float16)s[i];
}

__global__ __launch_bounds__(256)
void build_wcat(const float* __restrict__ Wih, const float* __restrict__ Whh,
                _Float16* __restrict__ d)
{
    const int i = blockIdx.x * 256 + threadIdx.x;   // over 1024*512
    const int row = i >> 9, col = i & 511;
    const float v = (col < 256) ? Wih[row * 256 + col] : Whh[row * 256 + col - 256];
    d[i] = (_Float16)v;
}

__global__ __launch_bounds__(256)
void add_bias(const float* __restrict__ a, const float* __restrict__ b,
              float* __restrict__ d)
{
    const int i = blockIdx.x * 256 + threadIdx.x;
    d[i] = a[i] + b[i];
}

// ---------------- first layer: u1 = relu(x @ Wi1^T + bi1), K=6, fp16 out ---
__global__ __launch_bounds__(256)
void in_mlp1(const float* __restrict__ x, const float* __restrict__ Wi1,
             const float* __restrict__ bi1, _Float16* __restrict__ out)
{
    const int idx = blockIdx.x * 256 + threadIdx.x;   // over Mc*H
    const int col = idx & (kH - 1);
    const int row = idx >> 8;
    const float* xr = x + (size_t)row * kLag;
    const float* w  = Wi1 + col * kLag;
    float s = bi1[col];
#pragma unroll
    for (int k = 0; k < kLag; ++k) s = fmaf(xr[k], w[k], s);
    out[idx] = (_Float16)fmaxf(s, 0.f);
}

// ---------------- fp16 MFMA GEMM v2 (unchanged, validated) -----------------
__global__ __launch_bounds__(256)
void gemm_h16(const _Float16* __restrict__ A, const _Float16* __restrict__ W,
              const float* __restrict__ bias, _Float16* __restrict__ C)
{
    const int tid = threadIdx.x;
    const int w = tid >> 6, lane = tid & 63, q = lane >> 4, l15 = lane & 15;
    const int n0 = blockIdx.x * 64;
    const int r0 = blockIdx.y * 128 + w * 32;

    half8 bf[4][8];
#pragma unroll
    for (int nt = 0; nt < 4; ++nt)
#pragma unroll
        for (int kk = 0; kk < 8; ++kk)
            bf[nt][kk] = *(const half8*)(W + (size_t)(n0 + nt * 16 + l15) * 256
                                         + kk * 32 + q * 8);
    float bz[4];
#pragma unroll
    for (int nt = 0; nt < 4; ++nt) bz[nt] = bias[n0 + nt * 16 + l15];

#pragma unroll
    for (int rt = 0; rt < 2; ++rt) {
        const _Float16* arow = A + (size_t)(r0 + rt * 16 + l15) * 256 + q * 8;
        half8 af[8];
#pragma unroll
        for (int kk = 0; kk < 8; ++kk) af[kk] = *(const half8*)(arow + kk * 32);
        f32x4 acc[4];
#pragma unroll
        for (int nt = 0; nt < 4; ++nt)
            acc[nt] = (f32x4){bz[nt], bz[nt], bz[nt], bz[nt]};
#pragma unroll
        for (int kk = 0; kk < 8; ++kk)
#pragma unroll
            for (int nt = 0; nt < 4; ++nt)
                acc[nt] = __builtin_amdgcn_mfma_f32_16x16x32_f16(
                    af[kk], bf[nt][kk], acc[nt], 0, 0, 0);
#pragma unroll
        for (int nt = 0; nt < 4; ++nt)
#pragma unroll
            for (int r = 0; r < 4; ++r) {
                const float v = fmaxf(acc[nt][r], 0.f);
                C[(size_t)(r0 + rt * 16 + q * 4 + r) * 256 + n0 + nt * 16 + l15]
                    = (_Float16)v;
            }
    }
}

// ---------------- persistent LSTM helpers ----------------------------------
__device__ __forceinline__ void gstore(float* __restrict__ gl, int m0, int nb,
                                       int q, int l15,
                                       const f32x4& a0, const f32x4& a1)
{
#pragma unroll
    for (int r = 0; r < 4; ++r) {
        gl[(m0 + q*4 + r) * kGS + nb + l15]      = a0[r];
        gl[(m0 + q*4 + r) * kGS + nb + 16 + l15] = a1[r];
    }
}

// layer-1 full gate GEMM: A = [h0(t) || h1(t-1)], 2 row-tiles sequential
__device__ __forceinline__ void phase_gemm_l1(
    const _Float16* __restrict__ lo, const _Float16* __restrict__ hi,
    const half8 (&B0)[16], const half8 (&B1)[16],
    float* __restrict__ gl, int rtb, int nb, int q, int l15)
{
#pragma unroll
    for (int rt = 0; rt < 2; ++rt) {
        const int row = (rtb + rt) * 16 + l15;
        const _Float16* plo = lo + (size_t)row * 256 + q * 8;
        const _Float16* phi = hi + (size_t)row * 256 + q * 8;
        half8 A[16];
#pragma unroll
        for (int kk = 0; kk < 8; ++kk) {
            ld_l2(A[kk], plo + kk * 32);
            ld_l2(A[8 + kk], phi + kk * 32);
        }
        WAITCNT_HOLD16(A);
        f32x4 a0 = {0.f,0.f,0.f,0.f}, a1 = {0.f,0.f,0.f,0.f};
#pragma unroll
        for (int kk = 0; kk < 16; ++kk) {
            a0 = __builtin_amdgcn_mfma_f32_16x16x32_f16(A[kk], B0[kk], a0, 0,0,0);
            a1 = __builtin_amdgcn_mfma_f32_16x16x32_f16(A[kk], B1[kk], a1, 0,0,0);
        }
        gstore(gl, (rtb + rt) * 16, nb, q, l15, a0, a1);
    }
}

// layer-0 u-half pre-work: acc = u(t') @ W[K 0..255]  (plain loads, no barrier
// dependency — runs inside the poll window, accs held across the barrier)
__device__ __forceinline__ void prework_u(
    const _Float16* __restrict__ lo,
    const half8 (&B0)[16], const half8 (&B1)[16],
    int rtb, int q, int l15, f32x4 (&acc)[2][2])
{
#pragma unroll
    for (int rt = 0; rt < 2; ++rt) {
        const int row = (rtb + rt) * 16 + l15;
        const _Float16* plo = lo + (size_t)row * 256 + q * 8;
        half8 A[8];
#pragma unroll
        for (int kk = 0; kk < 8; ++kk) ld_pln(A[kk], plo + kk * 32);
        WAITCNT_HOLD8(A);
        acc[rt][0] = (f32x4){0.f,0.f,0.f,0.f};
        acc[rt][1] = (f32x4){0.f,0.f,0.f,0.f};
#pragma unroll
        for (int kk = 0; kk < 8; ++kk) {
            acc[rt][0] = __builtin_amdgcn_mfma_f32_16x16x32_f16(
                A[kk], B0[kk], acc[rt][0], 0,0,0);
            acc[rt][1] = __builtin_amdgcn_mfma_f32_16x16x32_f16(
                A[kk], B1[kk], acc[rt][1], 0,0,0);
        }
    }
}

// layer-0 h-half finish: acc += h0(t) @ W[K 256..511]; store gates
__device__ __forceinline__ void finish_h(
    const _Float16* __restrict__ hi,
    const half8 (&B0)[16], const half8 (&B1)[16],
    float* __restrict__ gl, int rtb, int nb, int q, int l15,
    f32x4 (&acc)[2][2])
{
#pragma unroll
    for (int rt = 0; rt < 2; ++rt) {
        const int row = (rtb + rt) * 16 + l15;
        const _Float16* phi = hi + (size_t)row * 256 + q * 8;
        half8 A[8];
#pragma unroll
        for (int kk = 0; kk < 8; ++kk) ld_l2(A[kk], phi + kk * 32);
        WAITCNT_HOLD8(A);
#pragma unroll
        for (int kk = 0; kk < 8; ++kk) {
            acc[rt][0] = __builtin_amdgcn_mfma_f32_16x16x32_f16(
                A[kk], B0[8 + kk], acc[rt][0], 0,0,0);
            acc[rt][1] = __builtin_amdgcn_mfma_f32_16x16x32_f16(
                A[kk], B1[8 + kk], acc[rt][1], 0,0,0);
        }
        gstore(gl, (rtb + rt) * 16, nb, q, l15, acc[rt][0], acc[rt][1]);
    }
}

// cell: h + relu->u stored with PLAIN stores (land in the shared XCD L2)
__device__ __forceinline__ void cell_one(const float* __restrict__ gl,
    int crow, int cc, const float* __restrict__ bs, float* __restrict__ cst,
    _Float16* __restrict__ hout, _Float16* __restrict__ uout)
{
    const float* gr = gl + crow * kGS;
    _Float16 hp[2];
#pragma unroll
    for (int e = 0; e < 2; ++e) {
        const float gi = gr[0*16 + cc + e] + bs[e*4 + 0];
        const float gf = gr[1*16 + cc + e] + bs[e*4 + 1];
        const float gg = gr[2*16 + cc + e] + bs[e*4 + 2];
        const float go = gr[3*16 + cc + e] + bs[e*4 + 3];
        const float c2 = sigm(gf) * cst[e] + sigm(gi) * tanh_(gg);
        cst[e] = c2;
        hp[e] = (_Float16)(sigm(go) * tanh_(c2));
    }
    *(half2*)(hout + (size_t)crow * 256 + cc) = (half2){hp[0], hp[1]};
    if (uout) {
        const _Float16 z = (_Float16)0.f;
        *(half2*)(uout + (size_t)crow * 256 + cc) =
            (half2){hp[0] > z ? hp[0] : z, hp[1] > z ? hp[1] : z};
    }
}

// ---------------- persistent LSTM kernel -----------------------------------
__global__ __launch_bounds__(512, 2)
void lstm_all(_Float16* __restrict__ ubuf,
              const _Float16* __restrict__ Wc0, const _Float16* __restrict__ Wc1,
              const float* __restrict__ bc0, const float* __restrict__ bc1,
              _Float16* __restrict__ h0b, _Float16* __restrict__ h1b,
              unsigned int* __restrict__ cnt)
{
    extern __shared__ char lds[];
    float* gl0 = (float*)lds;             // [64][kGS] layer-0 gates
    float* gl1 = gl0 + 64 * kGS;          // [64][kGS] layer-1 gates

    const int tid = threadIdx.x;
    const int w = tid >> 6, lane = tid & 63, q = lane >> 4, l15 = lane & 15;
    const int wl = w & 3;
    const int rtb = (wl >> 1) * 2;        // row-tile base (0 or 2)
    const int nb  = (wl & 1) * 32;        // gate-col base (0 or 32)
    const int lyr = (w < 4) ? 1 : 0;      // wave's layer

    // ---- XCD discovery -> (bi, js): 96KB LDS => 1 block/CU => 32/XCD ----
    __shared__ int sh_bi, sh_js;
    if (tid == 0) {
        unsigned int xcd = __builtin_amdgcn_s_getreg(20 | (31 << 11)) & 7u;
        unsigned int rank = __hip_atomic_fetch_add(cnt + 512 + xcd * 16, 1u,
            __ATOMIC_RELAXED, __HIP_MEMORY_SCOPE_AGENT);
        sh_bi = (int)(xcd * 2 + (rank >> 4));
        sh_js = (int)(rank & 15);
    }
    __syncthreads();
    const int bi = sh_bi, js = sh_js;
    unsigned int* cptr = cnt + bi * 32;   // group counter line

    // ---- B-fragments of this wave's layer/cols -> 32 half8 in registers ----
    const _Float16* WcL = lyr ? Wc1 : Wc0;
    half8 Bf0[16], Bf1[16];
    {
        const _Float16* wr0 = WcL
            + (size_t)((nb >> 4) * 256 + js * 16 + l15) * 512 + q * 8;
        const _Float16* wr1 = WcL
            + (size_t)(((nb >> 4) + 1) * 256 + js * 16 + l15) * 512 + q * 8;
#pragma unroll
        for (int kk = 0; kk < 16; ++kk) {
            Bf0[kk] = *(const half8*)(wr0 + kk * 32);
            Bf1[kk] = *(const half8*)(wr1 + kk * 32);
        }
    }

    // ---- per-thread biases / states (cell: row tid>>3, cols cc, cc+1) ----
    const int cc = (tid & 7) * 2;
    const int crow = tid >> 3;
    float bs0[8], bs1[8];
#pragma unroll
    for (int e = 0; e < 2; ++e)
#pragma unroll
        for (int g = 0; g < 4; ++g) {
            bs0[e*4 + g] = bc0[g * 256 + js * 16 + cc + e];
            bs1[e*4 + g] = bc1[g * 256 + js * 16 + cc + e];
        }
    float cst0[2] = {0.f, 0.f}, cst1[2] = {0.f, 0.f};
    const size_t rbase = (size_t)bi * 64 * 256;
    const size_t obase = rbase + js * 16;

    f32x4 accB[2][2];                     // layer-0 partial gates (held)

    // ---- prologue: h0(0) = cell(u(0) @ W0_lo^T) -> h0b parity 0 ----
    if (lyr == 0) {
        prework_u(ubuf + rbase, Bf0, Bf1, rtb, q, l15, accB);
        gstore(gl0, rtb * 16, nb, q, l15, accB[0][0], accB[0][1]);
        gstore(gl0, (rtb + 1) * 16, nb, q, l15, accB[1][0], accB[1][1]);
    }
    __syncthreads();
    cell_one(gl0, crow, cc, bs0, cst0, h0b + obase, nullptr);
    // arrive, pre-work u(1), then release-wait
    asm volatile("s_waitcnt vmcnt(0)" ::: "memory");
    __syncthreads();
    if (tid == 0) atomic_add_nr(cptr, 1u);
    if (lyr == 0)
        prework_u(ubuf + (size_t)1 * kB * 256 + rbase, Bf0, Bf1,
                  rtb, q, l15, accB);
    if (tid == 0) {
        while (atomic_rd(cptr) < 16u) __builtin_amdgcn_s_sleep(1);
    }
    __syncthreads();

    // ---- fused phases: t computes h1(t) (waves 0-3) + h0(t+1) (waves 4-7) --
    for (int t = 0; t < kT; ++t) {
        const size_t p  = (size_t)(t & 1) * kB * 256;
        const size_t pn = (size_t)((t & 1) ^ 1) * kB * 256;
        const bool hasB = (t < kT - 1);
        if (lyr == 1) {
            phase_gemm_l1(h0b + p + rbase, h1b + pn + rbase,
                          Bf0, Bf1, gl1, rtb, nb, q, l15);
        } else if (hasB) {
            finish_h(h0b + p + rbase, Bf0, Bf1, gl0, rtb, nb, q, l15, accB);
        }
        __syncthreads();
        cell_one(gl1, crow, cc, bs1, cst1, h1b + p + obase,
                 ubuf + (size_t)t * kB * 256 + obase);
        if (hasB) {
            cell_one(gl0, crow, cc, bs0, cst0, h0b + pn + obase, nullptr);
            // arrive, pre-work u(t+2), release-wait
            asm volatile("s_waitcnt vmcnt(0)" ::: "memory");
            __syncthreads();
            if (tid == 0) atomic_add_nr(cptr, 1u);
            if (lyr == 0 && t < kT - 2)
                prework_u(ubuf + (size_t)(t + 2) * kB * 256 + rbase,
                          Bf0, Bf1, rtb, q, l15, accB);
            if (tid == 0) {
                const unsigned int tgt = (unsigned)(16 * (t + 2));
                while (atomic_rd(cptr) < tgt) __builtin_amdgcn_s_sleep(1);
            }
            __syncthreads();
        }
    }
}

// ---------------- last layer: y = y2 @ Wo3^T + bo3, N=6, fp16 in -----------
__global__ __launch_bounds__(256)
void out_mlp3(const _Float16* __restrict__ y2, const float* __restrict__ Wo3,
              const float* __restrict__ bo3, float* __restrict__ out)
{
    const int lane = threadIdx.x & 63;
    const int row  = blockIdx.x * 4 + (threadIdx.x >> 6);
    const _Float16* yr = y2 + (size_t)row * kH + lane * 4;
    const float a0 = (float)yr[0], a1 = (float)yr[1], a2 = (float)yr[2], a3 = (float)yr[3];
    float s[kLag];
#pragma unroll
    for (int o = 0; o < kLag; ++o) {
        const float4 wv = *(const float4*)(Wo3 + o * kH + lane * 4);
        s[o] = a0 * wv.x + a1 * wv.y + a2 * wv.z + a3 * wv.w;
    }
#pragma unroll
    for (int off = 32; off > 0; off >>= 1) {
#pragma unroll
        for (int o = 0; o < kLag; ++o) s[o] += __shfl_down(s[o], off);
    }
    if (lane == 0) {
#pragma unroll
        for (int o = 0; o < kLag; ++o)
            out[(size_t)row * kLag + o] = s[o] + bo3[o];
    }
}

// ---------------------------------------------------------------------------
extern "C" void kernel_launch(void* const* d_in, const int* in_sizes, int n_in,
                              void* d_out, int out_size, void* d_ws, size_t ws_size,
                              hipStream_t stream)
{
    const float* x    = (const float*)d_in[0];
    const float* Wi1  = (const float*)d_in[1];
    const float* bi1  = (const float*)d_in[2];
    const float* Wi2  = (const float*)d_in[3];
    const float* bi2  = (const float*)d_in[4];
    const float* Wi3  = (const float*)d_in[5];
    const float* bi3  = (const float*)d_in[6];
    const float* Wih0 = (const float*)d_in[7];
    const float* Whh0 = (const float*)d_in[8];
    const float* bih0 = (const float*)d_in[9];
    const float* bhh0 = (const float*)d_in[10];
    const float* Wih1 = (const float*)d_in[11];
    const float* Whh1 = (const float*)d_in[12];
    const float* bih1 = (const float*)d_in[13];
    const float* bhh1 = (const float*)d_in[14];
    const float* Wo1  = (const float*)d_in[15];
    const float* bo1  = (const float*)d_in[16];
    const float* Wo2  = (const float*)d_in[17];
    const float* bo2  = (const float*)d_in[18];
    const float* Wo3  = (const float*)d_in[19];
    const float* bo3  = (const float*)d_in[20];
    float* outp = (float*)d_out;

    // ---- workspace layout (~105 MB) ----
    char* p = (char*)d_ws;
    _Float16* ubuf = (_Float16*)p;  p += (size_t)kT * kB * kH * 2;   // 67.1 MB
    _Float16* s1   = (_Float16*)p;  p += (size_t)kMc * kH * 2;       // 33.5 MB
    _Float16* Wc0  = (_Float16*)p;  p += (size_t)1024 * 512 * 2;     // 1 MB
    _Float16* Wc1  = (_Float16*)p;  p += (size_t)1024 * 512 * 2;     // 1 MB
    _Float16* W2h  = (_Float16*)p;  p += (size_t)kH * kH * 2;
    _Float16* W3h  = (_Float16*)p;  p += (size_t)kH * kH * 2;
    _Float16* Wo1h = (_Float16*)p;  p += (size_t)kH * kH * 2;
    _Float16* Wo2h = (_Float16*)p;  p += (size_t)kH * kH * 2;
    float* bc0 = (float*)p;  p += 1024 * 4;
    float* bc1 = (float*)p;  p += 1024 * 4;
    // zeroed region: h double-buffers + counters (contiguous)
    _Float16* h0b = (_Float16*)p;  p += (size_t)2 * kB * kH * 2;     // 1 MB
    _Float16* h1b = (_Float16*)p;  p += (size_t)2 * kB * kH * 2;     // 1 MB
    unsigned int* cnt = (unsigned int*)p;  p += 4096;  // 16 group + 8 xcd ctrs

    // ---- prep ----
    zero_fill<<<2052, 256, 0, stream>>>((unsigned int*)h0b);
    cvt_f2h<<<kH * kH / 256, 256, 0, stream>>>(Wi2, W2h);
    cvt_f2h<<<kH * kH / 256, 256, 0, stream>>>(Wi3, W3h);
    cvt_f2h<<<kH * kH / 256, 256, 0, stream>>>(Wo1, Wo1h);
    cvt_f2h<<<kH * kH / 256, 256, 0, stream>>>(Wo2, Wo2h);
    build_wcat<<<1024 * 512 / 256, 256, 0, stream>>>(Wih0, Whh0, Wc0);
    build_wcat<<<1024 * 512 / 256, 256, 0, stream>>>(Wih1, Whh1, Wc1);
    add_bias<<<4, 256, 0, stream>>>(bih0, bhh0, bc0);
    add_bias<<<4, 256, 0, stream>>>(bih1, bhh1, bc1);

    // ---- input MLP (chunked, ubuf in-place): x -> ubuf -> s1 -> ubuf ----
    for (int c = 0; c < kT / kTc; ++c) {
        _Float16* ub = ubuf + (size_t)c * kMc * kH;
        in_mlp1<<<kMc * kH / 256, 256, 0, stream>>>(
            x + (size_t)c * kMc * kLag, Wi1, bi1, ub);
        gemm_h16<<<dim3(4, kMc / 128), 256, 0, stream>>>(ub, W2h, bi2, s1);
        gemm_h16<<<dim3(4, kMc / 128), 256, 0, stream>>>(s1, W3h, bi3, ub);
    }

    // ---- LSTM: cooperative, barrier-overlapped pre-work ----
    static bool attr_set = false;
    if (!attr_set) {
        hipFuncSetAttribute((const void*)lstm_all,
                            hipFuncAttributeMaxDynamicSharedMemorySize, kLdsForce);
        attr_set = true;
    }
    void* args[] = {&ubuf, &Wc0, &Wc1, &bc0, &bc1, &h0b, &h1b, &cnt};
    hipLaunchCooperativeKernel((const void*)lstm_all, dim3(256), dim3(512),
                               args, kLdsForce, stream);

    // ---- output MLP (chunked, ubuf in-place): ubuf -> s1 -> ubuf -> out ----
    for (int c = 0; c < kT / kTc; ++c) {
        _Float16* ub = ubuf + (size_t)c * kMc * kH;
        gemm_h16<<<dim3(4, kMc / 128), 256, 0, stream>>>(ub, Wo1h, bo1, s1);
        gemm_h16<<<dim3(4, kMc / 128), 256, 0, stream>>>(s1, Wo2h, bo2, ub);
        out_mlp3<<<kMc / 4, 256, 0, stream>>>(
            ub, Wo3, bo3, outp + (size_t)c * kMc * kLag);
    }
}